// Round 12
// baseline (1057.667 us; speedup 1.0000x reference)
//
#include <hip/hip_runtime.h>
#include <hip/hip_bf16.h>

typedef __bf16 bf16;
typedef bf16 bf16x8 __attribute__((ext_vector_type(8)));
typedef float f32x4 __attribute__((ext_vector_type(4)));

__device__ __forceinline__ void glds16(const void* g, void* l) {
    __builtin_amdgcn_global_load_lds(
        (const __attribute__((address_space(1))) void*)g,
        (__attribute__((address_space(3))) void*)l, 16, 0, 0);
}
__device__ __forceinline__ void glds16_byp(const void* g, void* l) {   // sc0|sc1
    __builtin_amdgcn_global_load_lds(
        (const __attribute__((address_space(1))) void*)g,
        (__attribute__((address_space(3))) void*)l, 16, 0, 17);
}

__device__ __forceinline__ float sigm(float x) { return 1.0f / (1.0f + __expf(-x)); }
__device__ __forceinline__ float tanh_f(float x) { return 2.0f / (1.0f + __expf(-2.0f * x)) - 1.0f; }

// ---------------------------------------------------------------------------
// fp32 -> bf16 conversion of x + 11 matrices into one packed ws area.
// ---------------------------------------------------------------------------
struct Cvt11 { const float* src[11]; unsigned gcnt[11]; };  // gcnt = elems/8

__global__ __launch_bounds__(256) void cvt_all(Cvt11 a, bf16* __restrict__ dst,
                                               unsigned total_g) {
    unsigned g = blockIdx.x * 256 + threadIdx.x;
    if (g >= total_g) return;
    unsigned s = 0, base = 0;
    while (g >= base + a.gcnt[s]) { base += a.gcnt[s]; ++s; }
    const float* sp = a.src[s] + (size_t)(g - base) * 8;
    float4 v0 = ((const float4*)sp)[0];
    float4 v1 = ((const float4*)sp)[1];
    bf16x8 o;
    o[0] = (bf16)v0.x; o[1] = (bf16)v0.y; o[2] = (bf16)v0.z; o[3] = (bf16)v0.w;
    o[4] = (bf16)v1.x; o[5] = (bf16)v1.y; o[6] = (bf16)v1.z; o[7] = (bf16)v1.w;
    *(bf16x8*)(dst + (size_t)g * 8) = o;
}

// Pack WcP[oct=68][2048][8]: oct o holds k-cols o*8..o*8+7 of
// Wcomb[2048,544] = Whh[2048,512] || Wih[2048,16] || zeros[16], bf16.
__global__ __launch_bounds__(128) void pack_w(const float* __restrict__ Whh,
                                              const float* __restrict__ Wih,
                                              bf16* __restrict__ WcP) {
    int row = blockIdx.x, seg = threadIdx.x;
    if (seg >= 68) return;
    bf16x8 o = {};
    if (seg < 64) {
        const float* sp = Whh + (size_t)row * 512 + seg * 8;
        float4 v0 = ((const float4*)sp)[0];
        float4 v1 = ((const float4*)sp)[1];
        o[0]=(bf16)v0.x; o[1]=(bf16)v0.y; o[2]=(bf16)v0.z; o[3]=(bf16)v0.w;
        o[4]=(bf16)v1.x; o[5]=(bf16)v1.y; o[6]=(bf16)v1.z; o[7]=(bf16)v1.w;
    } else if (seg < 66) {
        const float* sp = Wih + (size_t)row * 16 + (seg - 64) * 8;
        float4 v0 = ((const float4*)sp)[0];
        float4 v1 = ((const float4*)sp)[1];
        o[0]=(bf16)v0.x; o[1]=(bf16)v0.y; o[2]=(bf16)v0.z; o[3]=(bf16)v0.w;
        o[4]=(bf16)v1.x; o[5]=(bf16)v1.y; o[6]=(bf16)v1.z; o[7]=(bf16)v1.w;
    }
    *(bf16x8*)(WcP + ((size_t)seg * 2048 + row) * 8) = o;
}

// zero barrier records (must re-init every launch: ws is re-poisoned)
__global__ __launch_bounds__(512) void init_bvars(unsigned* __restrict__ bvars) {
    int t = threadIdx.x;
    for (int i = 0; i < 4; ++i) bvars[i * 512 + t] = 0u;
}

// ---------------------------------------------------------------------------
// GEMM: C[M,N](ldc) = act(A[M,K] @ W[N,K]^T + bias).  (prologue, verified)
// ---------------------------------------------------------------------------
template <int ACT, typename OutT>
__global__ __launch_bounds__(256) void gemm_bt(
    const bf16* __restrict__ A, const bf16* __restrict__ W,
    const float* __restrict__ bias, OutT* __restrict__ C,
    int M, int N, int K, int ldc)
{
    __shared__ __attribute__((aligned(16))) bf16 sA[64 * 32];
    __shared__ __attribute__((aligned(16))) bf16 sB[128 * 32];
    const int t = threadIdx.x;
    const int lane = t & 63, w = t >> 6;
    const int wm = w >> 1, wn = w & 1;
    const int quad = lane >> 4, l16 = lane & 15;
    const int m0 = blockIdx.y * 64, n0 = blockIdx.x * 128;

    f32x4 acc[2][4] = {};
    const int nk = K >> 5;
    for (int kc = 0; kc < nk; ++kc) {
        const int k0 = kc << 5;
        if (kc) __syncthreads();
        {
            int row = t >> 2, kof = (t & 3) << 3;
            glds16(A + (size_t)(m0 + row) * K + k0 + kof, (char*)sA + (w << 10));
        }
        for (int i = 0; i < 2; ++i) {
            int gi = (i << 8) + t;
            int row = gi >> 2, kof = (gi & 3) << 3;
            glds16(W + (size_t)(n0 + row) * K + k0 + kof,
                   (char*)sB + (i << 12) + (w << 10));
        }
        __syncthreads();
        bf16x8 af[2], bfr[4];
        for (int mi = 0; mi < 2; ++mi)
            af[mi] = *(const bf16x8*)(sA + ((wm * 32 + mi * 16 + l16) * 32 + quad * 8));
        for (int ni = 0; ni < 4; ++ni)
            bfr[ni] = *(const bf16x8*)(sB + ((wn * 64 + ni * 16 + l16) * 32 + quad * 8));
        for (int mi = 0; mi < 2; ++mi)
            for (int ni = 0; ni < 4; ++ni)
                acc[mi][ni] = __builtin_amdgcn_mfma_f32_16x16x32_bf16(
                    af[mi], bfr[ni], acc[mi][ni], 0, 0, 0);
    }
    for (int mi = 0; mi < 2; ++mi) {
        for (int ni = 0; ni < 4; ++ni) {
            int gn = n0 + wn * 64 + ni * 16 + l16;
            float bv = bias[gn];
            for (int r = 0; r < 4; ++r) {
                int gm = m0 + wm * 32 + mi * 16 + quad * 4 + r;
                float v = acc[mi][ni][r] + bv;
                if (ACT) v = v >= 0.f ? v : 0.2f * v;
                C[(size_t)gm * ldc + gn] = (OutT)v;
            }
        }
    }
}

// ---------------------------------------------------------------------------
// MFMA head (used once, for x0): writes softmax/sigmoid into xt0[4096][16].
// ---------------------------------------------------------------------------
__global__ __launch_bounds__(256) void head_mfma(
    const bf16* __restrict__ A, int lda,
    const bf16* __restrict__ Wp16,
    const float* __restrict__ bias,
    bf16* __restrict__ xt_dst, int ldx)
{
    const int t = threadIdx.x;
    const int lane = t & 63, w = t >> 6;
    const int quad = lane >> 4, l16 = lane & 15;
    const int r0 = blockIdx.x * 64 + w * 16;
    f32x4 acc = {};
    for (int kk = 0; kk < 16; ++kk) {
        bf16x8 a = *(const bf16x8*)(A + (size_t)(r0 + l16) * lda + kk * 32 + quad * 8);
        bf16x8 b = *(const bf16x8*)(Wp16 + (size_t)l16 * 512 + kk * 32 + quad * 8);
        acc = __builtin_amdgcn_mfma_f32_16x16x32_bf16(a, b, acc, 0, 0, 0);
    }
    const int n = l16;
    const float bv = bias[n];
    for (int r = 0; r < 4; ++r) {
        float p = acc[r] + bv;
        float vmax = (n == 15) ? -3.0e38f : p;
        for (int m = 1; m < 16; m <<= 1) vmax = fmaxf(vmax, __shfl_xor(vmax, m));
        float e = (n == 15) ? 0.f : __expf(p - vmax);
        float s = e;
        for (int m = 1; m < 16; m <<= 1) s += __shfl_xor(s, m);
        float res = (n == 15) ? sigm(p) : e / s;
        int gr = r0 + quad * 4 + r;
        xt_dst[(size_t)gr * ldx + n] = (bf16)res;
    }
}

// ---------------------------------------------------------------------------
// lstm_pair v2: 256 blocks = 128 pairs.  Block (rb=bid>>1, half=bid&1) owns
// 32 rows x 256 units -> per-CU B traffic HALVES to 1.11 MB/step (the
// measured ~85 GB/s/CU fetch path was the R7/R9 bound).  Per step the pair
// exchanges h-halves (16 KB each way) via the R6-verified scheme.
// FIX vs R11: at st==0 BOTH halves of h0 come from sH (full h0 loaded in
// init); xStg is only staged/valid for st>0.  R11 read uninitialized xStg
// at step 0 -> 1.37e-2 absmax.
// xt/head computed redundantly in both blocks (half==0 writes out).
// 122 KB LDS => 1 block/CU => 256 blocks all-resident by construction.
// ---------------------------------------------------------------------------
__global__ __launch_bounds__(512, 1) void lstm_pair(
    const bf16* __restrict__ h0g,   // [4096,512] h0 (prologue GEMM)
    const bf16* __restrict__ xt0,   // [4096,16]  x0-head (prologue)
    const bf16* __restrict__ WcP,   // [68][2048][8] oct-packed
    const bf16* __restrict__ Wp,    // [16,512]
    const float* __restrict__ bih, const float* __restrict__ bhh,
    const float* __restrict__ bp,
    const float* __restrict__ cb,   // [4096,512] fp32 c0
    bf16* __restrict__ hx,          // [2 parity][128 pair][2 half][8192] swz
    float* __restrict__ outp,       // [4096,512] = [B, T*16]
    unsigned* __restrict__ bvars)   // 128 pair records, 16 uints apart
{
    __shared__ __attribute__((aligned(16))) bf16 sH[2][32][552];  // 69 KB
    __shared__ __attribute__((aligned(16))) bf16 xStg[32 * 256];  // 16 KB partner
    __shared__ float sC[32 * 260];                                // 33.3 KB
    __shared__ float sBias[1024];                                 // 4 KB
    const int t = threadIdx.x;
    const int lane = t & 63, w = t >> 6;          // 8 waves
    const int quad = lane >> 4, l16 = lane & 15;
    const int bid = blockIdx.x;
    const int rb = bid >> 1, half = bid & 1;
    const int m0 = rb * 32, ub = half * 256;
    unsigned* grec = bvars + rb * 16;

    // ---- one-time init ----
    for (int i = 0; i < 2; ++i) {                 // sBias (own half, 4 gates)
        int idx = i * 512 + t, g = idx >> 8, ul = idx & 255;
        sBias[idx] = bih[(g << 9) + ub + ul] + bhh[(g << 9) + ub + ul];
    }
#pragma unroll
    for (int i = 0; i < 4; ++i) {                 // sC <- c0 own half
        int idx = i * 512 + t, row = idx >> 6, c4 = idx & 63;
        *(float4*)&sC[row * 260 + c4 * 4] =
            *(const float4*)(cb + (size_t)(m0 + row) * 512 + ub + c4 * 4);
    }
    for (int i = 0; i < 5; ++i) {                 // sH[0] <- FULL h0 || xt0 || 0
        int idx = i * 512 + t;
        if (idx < 2176) {
            int row = idx / 68, c8 = idx % 68, col = c8 * 8;
            bf16x8 v = {};
            if (col < 512)
                v = *(const bf16x8*)(h0g + (size_t)(m0 + row) * 512 + col);
            else if (col < 528)
                v = *(const bf16x8*)(xt0 + (size_t)(m0 + row) * 16 + (col - 512));
            *(bf16x8*)&sH[0][row][col] = v;
            if (col >= 528) *(bf16x8*)&sH[1][row][col] = v;  // zeros forever
        }
    }
    const int uw = w * 16 + l16;                  // unit-in-group 0..127
    const bf16* bb = WcP + (size_t)quad * 16384 + (size_t)(ub + uw) * 8;
    const float bp_l = bp[l16];
    __syncthreads();

#pragma unroll 1
    for (int st = 0; st <= 32; ++st) {
        const int hc = st & 1, hn = hc ^ 1;

        if (st > 0) {   // stage partner half of h_st (layout pre-swizzled)
            const bf16* src = hx + ((((size_t)hc) * 128 + rb) * 2 + (1 - half)) * 8192;
            for (int li = 0; li < 2; ++li)
                glds16_byp(src + (size_t)((li << 9) + t) * 8,
                           (char*)xStg + ((li << 9) + t) * 16);
        }
        __syncthreads();   // xStg ready; sH[hc] stable

        // ---- head (waves 0,1): xt_st = softmax(h_st @ Wp^T + bp) = ys[st-1]
        if (st > 0 && w < 2) {
            const int ri = w * 16 + l16;
            const int rx = (ri & 7) << 4;
            f32x4 pac = {};
#pragma unroll
            for (int kc = 0; kc < 16; ++kc) {
                bf16x8 af;
                if ((kc >> 3) == half)
                    af = *(const bf16x8*)&sH[hc][ri][kc * 32 + quad * 8];
                else
                    af = *(const bf16x8*)((const char*)xStg + ri * 512 +
                          ((((kc & 7) * 32 + quad * 8) * 2) ^ rx));
                bf16x8 wpf = *(const bf16x8*)(Wp + (size_t)l16 * 512 + kc * 32 + quad * 8);
                pac = __builtin_amdgcn_mfma_f32_16x16x32_bf16(af, wpf, pac, 0, 0, 0);
            }
#pragma unroll
            for (int r = 0; r < 4; ++r) {
                float pv = pac[r] + bp_l;
                float vmax = (l16 == 15) ? -3.0e38f : pv;
                for (int m = 1; m < 16; m <<= 1)
                    vmax = fmaxf(vmax, __shfl_xor(vmax, m));
                float e = (l16 == 15) ? 0.f : __expf(pv - vmax);
                float s = e;
                for (int m = 1; m < 16; m <<= 1) s += __shfl_xor(s, m);
                float res = (l16 == 15) ? sigm(pv) : e / s;
                int row = w * 16 + quad * 4 + r;
                if (st != 32) sH[hc][row][512 + l16] = (bf16)res;
                if (half == 0)
                    outp[(size_t)(m0 + row) * 512 + (st - 1) * 16 + l16] = res;
            }
        }
        __syncthreads();   // xt visible
        if (st == 32) break;

        // ---- main GEMM: 2 groups of 128 units (x4 gates), K = 17 chunks ----
        bf16* hxo = hx + ((((size_t)hn) * 128 + rb) * 2 + half) * 8192;
        const int rx0 = (l16 & 7) << 4;            // (16+l16)&7 == l16&7
#pragma unroll 1
        for (int nt = 0; nt < 2; ++nt) {
            const bf16* bnt = bb + (size_t)nt * 1024;
            f32x4 acc[2][4] = {};
            bf16x8 bfr[3][4];                      // R9's measured-best ring-3
#pragma unroll
            for (int ni = 0; ni < 4; ++ni) {
                bfr[0][ni] = *(const bf16x8*)(bnt + (size_t)ni * 4096);
                bfr[1][ni] = *(const bf16x8*)(bnt + (size_t)ni * 4096 + 65536);
            }
#pragma unroll
            for (int kc = 0; kc < 17; ++kc) {
                const int cur = kc % 3;
                if (kc < 15) {
#pragma unroll
                    for (int ni = 0; ni < 4; ++ni)
                        bfr[(kc + 2) % 3][ni] = *(const bf16x8*)
                            (bnt + (size_t)ni * 4096 + (size_t)(kc + 2) * 65536);
                }
                bf16x8 af0, af1;
                if (kc == 16) {
                    af0 = *(const bf16x8*)&sH[hc][l16][512 + quad * 8];
                    af1 = *(const bf16x8*)&sH[hc][16 + l16][512 + quad * 8];
                } else if (st == 0 || (kc >> 3) == half) {
                    // st==0: sH[0] holds the FULL h0 row (fix vs R11)
                    af0 = *(const bf16x8*)&sH[hc][l16][kc * 32 + quad * 8];
                    af1 = *(const bf16x8*)&sH[hc][16 + l16][kc * 32 + quad * 8];
                } else {
                    int ck2 = ((kc & 7) * 32 + quad * 8) * 2;
                    af0 = *(const bf16x8*)((const char*)xStg + l16 * 512 + (ck2 ^ rx0));
                    af1 = *(const bf16x8*)((const char*)xStg + (16 + l16) * 512 + (ck2 ^ rx0));
                }
#pragma unroll
                for (int ni = 0; ni < 4; ++ni) {
                    acc[0][ni] = __builtin_amdgcn_mfma_f32_16x16x32_bf16(
                        af0, bfr[cur][ni], acc[0][ni], 0, 0, 0);
                    acc[1][ni] = __builtin_amdgcn_mfma_f32_16x16x32_bf16(
                        af1, bfr[cur][ni], acc[1][ni], 0, 0, 0);
                }
            }
            // epilogue: gates -> c (LDS) -> h (sH + pre-swizzled hx store)
            const int ul = nt * 128 + uw;
#pragma unroll
            for (int mi = 0; mi < 2; ++mi) {
#pragma unroll
                for (int r = 0; r < 4; ++r) {
                    int row = mi * 16 + quad * 4 + r;
                    float i_ = sigm(acc[mi][0][r] + sBias[ul]);
                    float f_ = sigm(acc[mi][1][r] + sBias[256 + ul]);
                    float g_ = tanh_f(acc[mi][2][r] + sBias[512 + ul]);
                    float o_ = sigm(acc[mi][3][r] + sBias[768 + ul]);
                    int ci = row * 260 + ul;
                    float cn = f_ * sC[ci] + i_ * g_;
                    sC[ci] = cn;
                    float hv = o_ * tanh_f(cn);
                    bf16 hb = (bf16)hv;
                    sH[hn][row][ub + ul] = hb;
                    *(bf16*)((char*)hxo + row * 512 + ((ul * 2) ^ ((row & 7) << 4))) = hb;
                }
            }
        }

        __syncthreads();   // drain hx stores (vmcnt) before release
        if (t == 0) {      // pair barrier (R6-verified release/spin pattern)
            unsigned g0 = __hip_atomic_load(grec + 1, __ATOMIC_RELAXED,
                                            __HIP_MEMORY_SCOPE_AGENT);
            unsigned a = __hip_atomic_fetch_add(grec, 1u, __ATOMIC_RELEASE,
                                                __HIP_MEMORY_SCOPE_AGENT);
            if (a == 1u) {
                __hip_atomic_store(grec, 0u, __ATOMIC_RELAXED,
                                   __HIP_MEMORY_SCOPE_AGENT);
                __hip_atomic_fetch_add(grec + 1, 1u, __ATOMIC_RELEASE,
                                       __HIP_MEMORY_SCOPE_AGENT);
            } else {
                while (__hip_atomic_load(grec + 1, __ATOMIC_RELAXED,
                                         __HIP_MEMORY_SCOPE_AGENT) == g0)
                    __builtin_amdgcn_s_sleep(2);
            }
        }
        __syncthreads();
    }
}

// ---------------------------------------------------------------------------
extern "C" void kernel_launch(void* const* d_in, const int* in_sizes, int n_in,
                              void* d_out, int out_size, void* d_ws, size_t ws_size,
                              hipStream_t stream) {
    const float* xf   = (const float*)d_in[0];
    const float* W1f  = (const float*)d_in[1];  const float* b1  = (const float*)d_in[2];
    const float* W2f  = (const float*)d_in[3];  const float* b2  = (const float*)d_in[4];
    const float* W3f  = (const float*)d_in[5];  const float* b3  = (const float*)d_in[6];
    const float* Wh1f = (const float*)d_in[7];  const float* bh1 = (const float*)d_in[8];
    const float* Wh2f = (const float*)d_in[9];  const float* bh2 = (const float*)d_in[10];
    const float* Wc1f = (const float*)d_in[11]; const float* bc1 = (const float*)d_in[12];
    const float* Wc2f = (const float*)d_in[13]; const float* bc2 = (const float*)d_in[14];
    const float* Wx1f = (const float*)d_in[15]; const float* bx1 = (const float*)d_in[16];
    const float* Wx2f = (const float*)d_in[17]; const float* bx2 = (const float*)d_in[18];
    const float* Wihf = (const float*)d_in[19]; const float* bih = (const float*)d_in[20];
    const float* Whhf = (const float*)d_in[21]; const float* bhh = (const float*)d_in[22];
    const float* Wpf  = (const float*)d_in[23]; const float* bp  = (const float*)d_in[24];
    float* out = (float*)d_out;
    char* ws = (char*)d_ws;

    // layout (bytes): hx 0..8388608 (overlaps dead bufA/bufB) | hb0 8650752.. |
    // cb 13107200.. | WcP 21495808.. | cvt 23724032.. | bvars 28606464..
    bf16*  bufA = (bf16*)(ws + 0);
    bf16*  bufB = (bf16*)(ws + 4456448);
    bf16*  hx   = (bf16*)(ws + 0);            // loop-only; bufA/bufB dead by then
    bf16*  hb0  = (bf16*)(ws + 8650752);      // [4096,512]
    float* cb   = (float*)(ws + 13107200);    // [4096,512] fp32
    bf16*  WcP  = (bf16*)(ws + 21495808);     // [68][2048][8]
    bf16*  cvt  = (bf16*)(ws + 23724032);     // packed bf16 weights
    unsigned* bvars = (unsigned*)(ws + 28606464);  // 2048 uints

    const unsigned Ns[11] = {
        4096u * 128u,  // x
        512u * 128u,   // W1
        512u * 512u, 512u * 512u, 512u * 512u, 512u * 512u,  // W2,W3,Wh1,Wh2
        512u * 512u, 512u * 512u, 512u * 512u,               // Wc1,Wc2,Wx1
        16u * 512u,    // Wx2
        16u * 512u     // Wp
    };
    const float* srcs[11] = { xf, W1f, W2f, W3f, Wh1f, Wh2f, Wc1f, Wc2f,
                              Wx1f, Wx2f, Wpf };
    Cvt11 ca;
    unsigned off[12]; off[0] = 0;
    for (int i = 0; i < 11; ++i) {
        ca.src[i] = srcs[i];
        ca.gcnt[i] = Ns[i] >> 3;
        off[i + 1] = off[i] + Ns[i];
    }
    unsigned total_g = off[11] >> 3;
    cvt_all<<<dim3((total_g + 255) / 256), dim3(256), 0, stream>>>(ca, cvt, total_g);
    pack_w<<<dim3(2048), dim3(128), 0, stream>>>(Whhf, Wihf, WcP);

    const bf16* xb   = cvt + off[0];
    const bf16* W1b  = cvt + off[1];
    const bf16* W2b  = cvt + off[2];
    const bf16* W3b  = cvt + off[3];
    const bf16* Wh1b = cvt + off[4];
    const bf16* Wh2b = cvt + off[5];
    const bf16* Wc1b = cvt + off[6];
    const bf16* Wc2b = cvt + off[7];
    const bf16* Wx1b = cvt + off[8];
    const bf16* Wx2b = cvt + off[9];
    const bf16* Wpb  = cvt + off[10];
    // xt0 aliases the dead x slot (x only used by the first GEMM)
    bf16* xt0 = cvt + off[0];

    dim3 blk(256);
    dim3 gg(4, 64);  // N/128 x M/64
    gemm_bt<1, bf16 ><<<gg, blk, 0, stream>>>(xb,   W1b,  b1,  bufA, 4096, 512, 128, 512);
    gemm_bt<1, bf16 ><<<gg, blk, 0, stream>>>(bufA, W2b,  b2,  bufB, 4096, 512, 512, 512);
    gemm_bt<1, bf16 ><<<gg, blk, 0, stream>>>(bufB, W3b,  b3,  bufA, 4096, 512, 512, 512);
    gemm_bt<1, bf16 ><<<gg, blk, 0, stream>>>(bufA, Wh1b, bh1, bufB, 4096, 512, 512, 512);
    gemm_bt<0, bf16 ><<<gg, blk, 0, stream>>>(bufB, Wh2b, bh2, hb0,  4096, 512, 512, 512);
    gemm_bt<1, bf16 ><<<gg, blk, 0, stream>>>(bufA, Wc1b, bc1, bufB, 4096, 512, 512, 512);
    gemm_bt<0, float><<<gg, blk, 0, stream>>>(bufB, Wc2b, bc2, cb,   4096, 512, 512, 512);
    gemm_bt<1, bf16 ><<<gg, blk, 0, stream>>>(bufA, Wx1b, bx1, bufB, 4096, 512, 512, 512);
    init_bvars<<<dim3(1), dim3(512), 0, stream>>>(bvars);
    head_mfma<<<dim3(64), blk, 0, stream>>>(bufB, 512, Wx2b, bx2, xt0, 16);

    // 128 pairs x 2 blocks; per-CU B traffic halved; pair h-exchange
    lstm_pair<<<dim3(256), dim3(512), 0, stream>>>(hb0, xt0, WcP, Wpb,
                                                   bih, bhh, bp, cb,
                                                   hx, out, bvars);
}